// Round 5
// baseline (184.319 us; speedup 1.0000x reference)
//
#include <hip/hip_runtime.h>

#define B_    32
#define C_    512
#define HW2_  1024
#define NW    77
#define NP    80     // n padded to 80 (5 x 16 MFMA rows)
#define NPT   96     // n pitch for P (3 K-steps of 32), cols >=77: P=0
#define WD    256

typedef unsigned int   uint32;
typedef unsigned short u16;
typedef __attribute__((ext_vector_type(8))) short bf16x8;  // MFMA A/B frag (4 VGPR)
typedef __attribute__((ext_vector_type(4))) float f32x4;   // MFMA C/D frag

#define MFMA(a, b, c) __builtin_amdgcn_mfma_f32_16x16x32_bf16(a, b, c, 0, 0, 0)

// workspace element counts (bf16x8 = 16 B units)
// we planes:  [b][q=16][n=80][kloc=64]  -> idx = ((b*16+q)*80+n)*8 + kloc/8
// weT planes: [b][kout=1024][n=96]      -> idx = (b*1024+kout)*12 + n/8
#define WE_ELN   ((size_t)B_ * 16 * NP * 8)     // 327680
#define WET_ELN  ((size_t)B_ * HW2_ * 12)       // 393216

// fp32 -> (hi, lo) bf16 split. hi = truncation, residual exact, lo = RNE.
__device__ __forceinline__ void split1(float x, u16 &h, u16 &l) {
    uint32 u = __float_as_uint(x);
    h = (u16)(u >> 16);
    float r = x - __uint_as_float(u & 0xffff0000u);   // exact
    uint32 v = __float_as_uint(r);
    l = (u16)((v + 0x7fffu + ((v >> 16) & 1u)) >> 16);
}

__device__ __forceinline__ void split8(float4 a, float4 b, bf16x8 &h, bf16x8 &l) {
    float v[8] = {a.x, a.y, a.z, a.w, b.x, b.y, b.z, b.w};
    #pragma unroll
    for (int i = 0; i < 8; ++i) {
        u16 hh, ll; split1(v[i], hh, ll);
        h[i] = (short)hh; l[i] = (short)ll;
    }
}

// ---------------------------------------------------------------------------
// Kernel 1: we = word_emb @ W_fc^T + b_fc via MFMA (4-term split, in-reg
// fp32->bf16 splitting fused in — proven latency-hidden). W-row loads hoisted
// behind a sched_barrier wall. Outputs both layouts with contiguous stores.
// grid 512 = 32 b x 16 k-chunks, b -> XCD b%8 (matches attn).
// ---------------------------------------------------------------------------
__global__ __launch_bounds__(256, 2) void we_gemm(
    const float* __restrict__ word_emb, const float* __restrict__ W_fc,
    const float* __restrict__ b_fc,
    bf16x8* __restrict__ we_hi, bf16x8* __restrict__ we_lo,
    bf16x8* __restrict__ weT_hi, bf16x8* __restrict__ weT_lo)
{
    __shared__ __align__(16) uint32 HL[NP][68];   // (hi<<16)|lo, 21.8 KB

    const int id = blockIdx.x;
    const int b  = (id & 7) + 8 * (id >> 7);      // XCD = id%8 = b%8
    const int q  = (id >> 3) & 15;
    const int kb = q * 64;
    const int t  = threadIdx.x;
    const int w  = t >> 6, lane = t & 63, lr = lane & 15, lg = lane >> 4;
    const int kout = kb + 16 * w + lr;

    // ---- hoist the full W row (this lane's 8 d-slices), wall off sinking --
    const float* wrow = W_fc + kout * WD;
    float4 wx[8], wy[8];
    #pragma unroll
    for (int ks = 0; ks < 8; ++ks) {
        const int dk = ks * 32 + 8 * lg;
        wx[ks] = *(const float4*)(wrow + dk);
        wy[ks] = *(const float4*)(wrow + dk + 4);
    }
    __builtin_amdgcn_sched_barrier(0);

    bf16x8 bh[8], bl[8];
    #pragma unroll
    for (int ks = 0; ks < 8; ++ks) split8(wx[ks], wy[ks], bh[ks], bl[ks]);

    f32x4 acc[5];
    #pragma unroll
    for (int m = 0; m < 5; ++m) acc[m] = (f32x4)0.0f;

    const float* emb = word_emb + b * NW * WD;

    #pragma unroll
    for (int ks = 0; ks < 8; ++ks) {
        const int dk = ks * 32 + 8 * lg;
        bf16x8 ah[5], al[5];
        #pragma unroll
        for (int m = 0; m < 5; ++m) {
            const int n = 16 * m + lr;
            float4 x = make_float4(0.f, 0.f, 0.f, 0.f), y = x;
            if (n < NW) {
                const float* p = emb + n * WD + dk;
                x = *(const float4*)p; y = *(const float4*)(p + 4);
            }
            split8(x, y, ah[m], al[m]);
        }
        #pragma unroll
        for (int m = 0; m < 5; ++m) {
            acc[m] = MFMA(ah[m], bh[ks], acc[m]);
            acc[m] = MFMA(ah[m], bl[ks], acc[m]);
            acc[m] = MFMA(al[m], bh[ks], acc[m]);
            acc[m] = MFMA(al[m], bl[ks], acc[m]);
        }
    }

    const float bias = b_fc[kout];
    #pragma unroll
    for (int m = 0; m < 5; ++m)
        #pragma unroll
        for (int r = 0; r < 4; ++r) {
            u16 hh, ll; split1(acc[m][r] + bias, hh, ll);
            HL[16 * m + 4 * lg + r][16 * w + lr] = ((uint32)hh << 16) | ll;
        }
    __syncthreads();

    // we planes: [b][q][n][64k] -> contiguous 10 KB run per plane per block
    #pragma unroll
    for (int u0 = 0; u0 < 640; u0 += 256) {
        const int u = u0 + t;
        if (u < 640) {
            const int n = u >> 3, c8 = (u & 7) * 8;
            uint4 p0 = *(const uint4*)&HL[n][c8];
            uint4 p1 = *(const uint4*)&HL[n][c8 + 4];
            const uint32 pw[8] = {p0.x, p0.y, p0.z, p0.w, p1.x, p1.y, p1.z, p1.w};
            bf16x8 hv, lv;
            #pragma unroll
            for (int i = 0; i < 8; ++i) {
                hv[i] = (short)(pw[i] >> 16);
                lv[i] = (short)(pw[i] & 0xffffu);
            }
            const int o = ((b * 16 + q) * NP + n) * 8 + (u & 7);
            we_hi[o] = hv; we_lo[o] = lv;
        }
    }
    // weT planes: [b][kout][96] -> consecutive threads write consecutive 16 B
    #pragma unroll
    for (int v0 = 0; v0 < 1536; v0 += 256) {
        const int v = v0 + t;
        const int sel = v >= 768;
        const int r2  = sel ? v - 768 : v;
        const int row = r2 / 12, g = r2 % 12;
        bf16x8 val;
        #pragma unroll
        for (int i = 0; i < 8; ++i) {
            const int n = g * 8 + i;
            const uint32 p = (n < NP) ? HL[n][row] : 0u;
            val[i] = (short)(sel ? (p & 0xffffu) : (p >> 16));
        }
        (sel ? weT_lo : weT_hi)[(b * HW2_ + kb + row) * 12 + g] = val;
    }
}

// ---------------------------------------------------------------------------
// Kernel 2: fused scores^T -> softmax -> out via MFMA (3-term split).
// Block = 32 c-rows (2 strips per wave), 4 waves = 4 K-quarters.
// ALL feat loads for phase 1 issued upfront behind a sched_barrier wall
// (~128 VGPR) so HBM latency is paid once, not 8x per wave.
// grid 512 = 32 b x 16 c-blocks -> 2 blocks/CU; XCD-swizzled per batch.
// ---------------------------------------------------------------------------
__global__ __launch_bounds__(256, 2) void attn_mfma(
    const float* __restrict__ feat,
    const bf16x8* __restrict__ we_hi, const bf16x8* __restrict__ we_lo,
    const bf16x8* __restrict__ weT_hi, const bf16x8* __restrict__ weT_lo,
    float* __restrict__ out)
{
    __shared__ __align__(16) float S[4][16][84];  // partial scores (21.5 KB)
    __shared__ __align__(16) u16   Ph[32][NPT];   // P hi (6 KB)
    __shared__ __align__(16) u16   Pl[32][NPT];   // P lo (6 KB)

    const int id  = blockIdx.x;
    const int b   = (id & 7) + 8 * (id >> 7);     // batch -> XCD id&7 (=b%8)
    const int c0  = ((id >> 3) & 15) * 32;        // block's 32 c rows

    const int t    = threadIdx.x;
    const int h    = t >> 6;                      // wave = K-quarter
    const int lane = t & 63, lr = lane & 15, lg = lane >> 4;

    // ---- Phase 1: hoist ALL feat loads (2 strips x 8 ks x 32 B) -----------
    const float* frow0 = feat + (size_t)(b * C_ + c0 + lr) * HW2_;
    const float* frow1 = frow0 + 16 * HW2_;

    float4 f0x[8], f0y[8], f1x[8], f1y[8];
    #pragma unroll
    for (int ks = 0; ks < 8; ++ks) {
        const int kk = h * 256 + ks * 32 + 8 * lg;
        f0x[ks] = *(const float4*)(frow0 + kk);
        f0y[ks] = *(const float4*)(frow0 + kk + 4);
        f1x[ks] = *(const float4*)(frow1 + kk);
        f1y[ks] = *(const float4*)(frow1 + kk + 4);
    }
    __builtin_amdgcn_sched_barrier(0);

    f32x4 acc[2][5];
    #pragma unroll
    for (int s = 0; s < 2; ++s)
        #pragma unroll
        for (int m = 0; m < 5; ++m) acc[s][m] = (f32x4)0.0f;

    #pragma unroll
    for (int ks = 0; ks < 8; ++ks) {
        bf16x8 fh0, fl0, fh1, fl1;
        split8(f0x[ks], f0y[ks], fh0, fl0);
        split8(f1x[ks], f1y[ks], fh1, fl1);
        const int qb  = (b * 16 + h * 4 + (ks >> 1)) * NP;
        const int sub = (ks & 1) * 4 + lg;
        #pragma unroll
        for (int m = 0; m < 5; ++m) {
            const int o = (qb + 16 * m + lr) * 8 + sub;
            const bf16x8 ah = we_hi[o];
            const bf16x8 al = we_lo[o];
            acc[0][m] = MFMA(ah, fh0, acc[0][m]);
            acc[0][m] = MFMA(ah, fl0, acc[0][m]);
            acc[0][m] = MFMA(al, fh0, acc[0][m]);
            acc[1][m] = MFMA(ah, fh1, acc[1][m]);
            acc[1][m] = MFMA(ah, fl1, acc[1][m]);
            acc[1][m] = MFMA(al, fh1, acc[1][m]);
        }
    }

    // ---- merge + softmax, one 16-row strip at a time -----------------------
    #pragma unroll
    for (int s = 0; s < 2; ++s) {
        #pragma unroll
        for (int m = 0; m < 5; ++m)
            #pragma unroll
            for (int r = 0; r < 4; ++r)
                S[h][lr][16 * m + 4 * lg + r] = acc[s][m][r];
        __syncthreads();
        {
            const int srow = 4 * h + (lane >> 4), scol = lane & 15;
            float v5[6];
            float mx = -3.0e38f;
            #pragma unroll
            for (int j = 0; j < 6; ++j) {
                const int n = scol + 16 * j;
                float sv = 0.f;
                if (j < 5) {
                    sv = S[0][srow][n] + S[1][srow][n] + S[2][srow][n] + S[3][srow][n];
                    if (n < NW) mx = fmaxf(mx, sv);
                }
                v5[j] = sv;
            }
            mx = fmaxf(mx, __shfl_xor(mx, 1));
            mx = fmaxf(mx, __shfl_xor(mx, 2));
            mx = fmaxf(mx, __shfl_xor(mx, 4));
            mx = fmaxf(mx, __shfl_xor(mx, 8));
            float sum = 0.f;
            #pragma unroll
            for (int j = 0; j < 6; ++j) {
                const int n = scol + 16 * j;
                const float e = (n < NW) ? __expf(v5[j] - mx) : 0.f;
                v5[j] = e; sum += e;
            }
            sum += __shfl_xor(sum, 1);
            sum += __shfl_xor(sum, 2);
            sum += __shfl_xor(sum, 4);
            sum += __shfl_xor(sum, 8);
            const float inv = 1.0f / sum;
            #pragma unroll
            for (int j = 0; j < 6; ++j) {
                const int n = scol + 16 * j;
                u16 ph, pl; split1(v5[j] * inv, ph, pl);
                Ph[16 * s + srow][n] = ph; Pl[16 * s + srow][n] = pl;
            }
        }
        __syncthreads();
    }

    // ---- Phase 3: out^T[kout][c] = weT . P^T; wave h owns kout quarter ----
    bf16x8 pbh[2][3], pbl[2][3];
    #pragma unroll
    for (int s = 0; s < 2; ++s)
        #pragma unroll
        for (int ksn = 0; ksn < 3; ++ksn) {
            pbh[s][ksn] = *(const bf16x8*)&Ph[16 * s + lr][32 * ksn + 8 * lg];
            pbl[s][ksn] = *(const bf16x8*)&Pl[16 * s + lr][32 * ksn + 8 * lg];
        }
    const bf16x8* th = weT_hi + (size_t)b * HW2_ * 12;
    const bf16x8* tl = weT_lo + (size_t)b * HW2_ * 12;
    float* orow0 = out + (size_t)(b * C_ + c0 + lr) * HW2_;
    float* orow1 = orow0 + 16 * HW2_;

    #pragma unroll
    for (int tt = 0; tt < 16; ++tt) {
        const int row = h * 256 + tt * 16 + lr;
        bf16x8 wa[3], wb[3];
        #pragma unroll
        for (int ksn = 0; ksn < 3; ++ksn) {
            wa[ksn] = th[row * 12 + 4 * ksn + lg];
            wb[ksn] = tl[row * 12 + 4 * ksn + lg];
        }
        f32x4 o0 = (f32x4)0.0f, o1 = (f32x4)0.0f;
        #pragma unroll
        for (int ksn = 0; ksn < 3; ++ksn) {
            o0 = MFMA(wa[ksn], pbh[0][ksn], o0);
            o0 = MFMA(wa[ksn], pbl[0][ksn], o0);
            o0 = MFMA(wb[ksn], pbh[0][ksn], o0);
            o1 = MFMA(wa[ksn], pbh[1][ksn], o1);
            o1 = MFMA(wa[ksn], pbl[1][ksn], o1);
            o1 = MFMA(wb[ksn], pbh[1][ksn], o1);
        }
        const int col = h * 256 + tt * 16 + 4 * lg;
        *(float4*)(orow0 + col) = make_float4(o0[0], o0[1], o0[2], o0[3]);
        *(float4*)(orow1 + col) = make_float4(o1[0], o1[1], o1[2], o1[3]);
    }
}

// ---------------------------------------------------------------------------
extern "C" void kernel_launch(void* const* d_in, const int* in_sizes, int n_in,
                              void* d_out, int out_size, void* d_ws, size_t ws_size,
                              hipStream_t stream) {
    (void)in_sizes; (void)n_in; (void)out_size; (void)ws_size;
    const float* feat     = (const float*)d_in[0];
    const float* word_emb = (const float*)d_in[1];
    const float* W_fc     = (const float*)d_in[2];
    const float* b_fc     = (const float*)d_in[3];

    bf16x8* we_hi  = (bf16x8*)d_ws;
    bf16x8* we_lo  = we_hi  + WE_ELN;
    bf16x8* weT_hi = we_lo  + WE_ELN;
    bf16x8* weT_lo = weT_hi + WET_ELN;

    we_gemm<<<512, 256, 0, stream>>>(word_emb, W_fc, b_fc, we_hi, we_lo, weT_hi, weT_lo);
    attn_mfma<<<512, 256, 0, stream>>>(feat, we_hi, we_lo, weT_hi, weT_lo, (float*)d_out);
}

// Round 6
// 179.758 us; speedup vs baseline: 1.0254x; 1.0254x over previous
//
#include <hip/hip_runtime.h>

#define B_    32
#define C_    512
#define HW2_  1024
#define NW    77
#define NP    80     // n padded to 80 (5 x 16 MFMA rows)
#define NPT   96     // n pitch for P (3 K-steps of 32), cols >=77: P=0
#define WD    256

typedef unsigned int   uint32;
typedef unsigned short u16;
typedef __attribute__((ext_vector_type(8))) short bf16x8;  // MFMA A/B frag (4 VGPR)
typedef __attribute__((ext_vector_type(4))) float f32x4;   // MFMA C/D frag

#define MFMA(a, b, c) __builtin_amdgcn_mfma_f32_16x16x32_bf16(a, b, c, 0, 0, 0)
#define SWALL() __builtin_amdgcn_sched_barrier(0)

// workspace element counts (bf16x8 = 16 B units)
// we planes:  [b][q=16][n=80][kloc=64]  -> idx = ((b*16+q)*80+n)*8 + kloc/8
// weT planes: [b][kout=1024][n=96]      -> idx = (b*1024+kout)*12 + n/8
#define WE_ELN   ((size_t)B_ * 16 * NP * 8)     // 327680
#define WET_ELN  ((size_t)B_ * HW2_ * 12)       // 393216

// fp32 -> (hi, lo) bf16 split. hi = truncation, residual exact, lo = RNE.
__device__ __forceinline__ void split1(float x, u16 &h, u16 &l) {
    uint32 u = __float_as_uint(x);
    h = (u16)(u >> 16);
    float r = x - __uint_as_float(u & 0xffff0000u);   // exact
    uint32 v = __float_as_uint(r);
    l = (u16)((v + 0x7fffu + ((v >> 16) & 1u)) >> 16);
}

__device__ __forceinline__ void split8(float4 a, float4 b, bf16x8 &h, bf16x8 &l) {
    float v[8] = {a.x, a.y, a.z, a.w, b.x, b.y, b.z, b.w};
    #pragma unroll
    for (int i = 0; i < 8; ++i) {
        u16 hh, ll; split1(v[i], hh, ll);
        h[i] = (short)hh; l[i] = (short)ll;
    }
}

// ---------------------------------------------------------------------------
// Kernel 1: we = word_emb @ W_fc^T + b_fc via MFMA (4-term split fused).
// W row hoisted; E loads 1-deep modulo prefetch behind sched_barrier walls.
// grid 512 = 32 b x 16 k-chunks, b -> XCD b%8 (matches attn).
// ---------------------------------------------------------------------------
__global__ __launch_bounds__(256, 2) void we_gemm(
    const float* __restrict__ word_emb, const float* __restrict__ W_fc,
    const float* __restrict__ b_fc,
    bf16x8* __restrict__ we_hi, bf16x8* __restrict__ we_lo,
    bf16x8* __restrict__ weT_hi, bf16x8* __restrict__ weT_lo)
{
    __shared__ __align__(16) uint32 HL[NP][68];   // (hi<<16)|lo, 21.8 KB

    const int id = blockIdx.x;
    const int b  = (id & 7) + 8 * (id >> 7);      // XCD = id%8 = b%8
    const int q  = (id >> 3) & 15;
    const int kb = q * 64;
    const int t  = threadIdx.x;
    const int w  = t >> 6, lane = t & 63, lr = lane & 15, lg = lane >> 4;
    const int kout = kb + 16 * w + lr;

    // ---- hoist the full W row (this lane's 8 d-slices) --------------------
    const float* wrow = W_fc + kout * WD;
    float4 wx[8], wy[8];
    #pragma unroll
    for (int ks = 0; ks < 8; ++ks) {
        const int dk = ks * 32 + 8 * lg;
        wx[ks] = *(const float4*)(wrow + dk);
        wy[ks] = *(const float4*)(wrow + dk + 4);
    }
    SWALL();
    bf16x8 bh[8], bl[8];
    #pragma unroll
    for (int ks = 0; ks < 8; ++ks) split8(wx[ks], wy[ks], bh[ks], bl[ks]);

    f32x4 acc[5];
    #pragma unroll
    for (int m = 0; m < 5; ++m) acc[m] = (f32x4)0.0f;

    const float* emb = word_emb + b * NW * WD;

    // ---- 1-deep modulo prefetch of the 10 E float4s -----------------------
    float4 ex[2][5], ey[2][5];
#define WG_E(sl, ksv) do {                                          \
        const int dk_ = (ksv) * 32 + 8 * lg;                        \
        _Pragma("unroll")                                           \
        for (int m_ = 0; m_ < 5; ++m_) {                            \
            const int n_ = 16 * m_ + lr;                            \
            if (n_ < NW) {                                          \
                const float* p_ = emb + n_ * WD + dk_;              \
                ex[sl][m_] = *(const float4*)p_;                    \
                ey[sl][m_] = *(const float4*)(p_ + 4);              \
            } else {                                                \
                ex[sl][m_] = make_float4(0.f, 0.f, 0.f, 0.f);       \
                ey[sl][m_] = make_float4(0.f, 0.f, 0.f, 0.f);       \
            }                                                       \
        } } while (0)

    WG_E(0, 0);
    SWALL();
    #pragma unroll
    for (int ks = 0; ks < 8; ++ks) {
        const int cur = ks & 1;
        if (ks < 7) WG_E(cur ^ 1, ks + 1);
        SWALL();
        bf16x8 ah[5], al[5];
        #pragma unroll
        for (int m = 0; m < 5; ++m) split8(ex[cur][m], ey[cur][m], ah[m], al[m]);
        #pragma unroll
        for (int m = 0; m < 5; ++m) {
            acc[m] = MFMA(ah[m], bh[ks], acc[m]);
            acc[m] = MFMA(ah[m], bl[ks], acc[m]);
            acc[m] = MFMA(al[m], bh[ks], acc[m]);
            acc[m] = MFMA(al[m], bl[ks], acc[m]);
        }
        SWALL();
    }
#undef WG_E

    const float bias = b_fc[kout];
    #pragma unroll
    for (int m = 0; m < 5; ++m)
        #pragma unroll
        for (int r = 0; r < 4; ++r) {
            u16 hh, ll; split1(acc[m][r] + bias, hh, ll);
            HL[16 * m + 4 * lg + r][16 * w + lr] = ((uint32)hh << 16) | ll;
        }
    __syncthreads();

    // we planes: [b][q][n][64k] -> contiguous runs
    #pragma unroll
    for (int u0 = 0; u0 < 640; u0 += 256) {
        const int u = u0 + t;
        if (u < 640) {
            const int n = u >> 3, c8 = (u & 7) * 8;
            uint4 p0 = *(const uint4*)&HL[n][c8];
            uint4 p1 = *(const uint4*)&HL[n][c8 + 4];
            const uint32 pw[8] = {p0.x, p0.y, p0.z, p0.w, p1.x, p1.y, p1.z, p1.w};
            bf16x8 hv, lv;
            #pragma unroll
            for (int i = 0; i < 8; ++i) {
                hv[i] = (short)(pw[i] >> 16);
                lv[i] = (short)(pw[i] & 0xffffu);
            }
            const int o = ((b * 16 + q) * NP + n) * 8 + (u & 7);
            we_hi[o] = hv; we_lo[o] = lv;
        }
    }
    // weT planes: [b][kout][96] -> consecutive threads write consecutive 16 B
    #pragma unroll
    for (int v0 = 0; v0 < 1536; v0 += 256) {
        const int v = v0 + t;
        const int sel = v >= 768;
        const int r2  = sel ? v - 768 : v;
        const int row = r2 / 12, g = r2 % 12;
        bf16x8 val;
        #pragma unroll
        for (int i = 0; i < 8; ++i) {
            const int n = g * 8 + i;
            const uint32 p = (n < NP) ? HL[n][row] : 0u;
            val[i] = (short)(sel ? (p & 0xffffu) : (p >> 16));
        }
        (sel ? weT_lo : weT_hi)[(b * HW2_ + kb + row) * 12 + g] = val;
    }
}

// ---------------------------------------------------------------------------
// Kernel 2: fused scores^T -> softmax -> out via MFMA (3-term split).
// Block = 32 c-rows (2 strips per wave), 4 waves = 4 K-quarters.
// Phase 1: feat 2-deep (HBM) + we 1-deep (L2) modulo prefetch with walls.
// Phase 3: weT 2-deep 3-slot ring with walls.
// grid 512 = 32 b x 16 c-blocks -> 2 blocks/CU; XCD-swizzled per batch.
// ---------------------------------------------------------------------------
__global__ __launch_bounds__(256, 2) void attn_mfma(
    const float* __restrict__ feat,
    const bf16x8* __restrict__ we_hi, const bf16x8* __restrict__ we_lo,
    const bf16x8* __restrict__ weT_hi, const bf16x8* __restrict__ weT_lo,
    float* __restrict__ out)
{
    __shared__ __align__(16) float S[4][16][84];  // partial scores (21.5 KB)
    __shared__ __align__(16) u16   Ph[32][NPT];   // P hi (6 KB)
    __shared__ __align__(16) u16   Pl[32][NPT];   // P lo (6 KB)

    const int id  = blockIdx.x;
    const int b   = (id & 7) + 8 * (id >> 7);     // batch -> XCD id&7 (=b%8)
    const int c0  = ((id >> 3) & 15) * 32;        // block's 32 c rows

    const int t    = threadIdx.x;
    const int h    = t >> 6;                      // wave = K-quarter
    const int lane = t & 63, lr = lane & 15, lg = lane >> 4;

    const float* frow0 = feat + (size_t)(b * C_ + c0 + lr) * HW2_;
    const float* frow1 = frow0 + 16 * HW2_;

    // ---- Phase 1: feat 2-deep (3-slot), we 1-deep (2-slot) prefetch -------
    float4 fx0[3], fy0[3], fx1[3], fy1[3];
    bf16x8 wph[2][5], wpl[2][5];

#define P1_FEAT(sl, ksv) do {                                       \
        const int kk_ = h * 256 + (ksv) * 32 + 8 * lg;              \
        fx0[sl] = *(const float4*)(frow0 + kk_);                    \
        fy0[sl] = *(const float4*)(frow0 + kk_ + 4);                \
        fx1[sl] = *(const float4*)(frow1 + kk_);                    \
        fy1[sl] = *(const float4*)(frow1 + kk_ + 4); } while (0)
#define P1_WE(sl, ksv) do {                                         \
        const int qb_  = (b * 16 + h * 4 + ((ksv) >> 1)) * NP;      \
        const int sub_ = ((ksv) & 1) * 4 + lg;                      \
        _Pragma("unroll")                                           \
        for (int m_ = 0; m_ < 5; ++m_) {                            \
            const int o_ = (qb_ + 16 * m_ + lr) * 8 + sub_;         \
            wph[sl][m_] = we_hi[o_];                                \
            wpl[sl][m_] = we_lo[o_];                                \
        } } while (0)

    f32x4 acc[2][5];
    #pragma unroll
    for (int s = 0; s < 2; ++s)
        #pragma unroll
        for (int m = 0; m < 5; ++m) acc[s][m] = (f32x4)0.0f;

    P1_FEAT(0, 0); P1_FEAT(1, 1); P1_WE(0, 0);
    SWALL();
    #pragma unroll
    for (int ks = 0; ks < 8; ++ks) {
        const int fc = ks % 3, wc = ks & 1;
        if (ks < 6) P1_FEAT((ks + 2) % 3, ks + 2);
        if (ks < 7) P1_WE(wc ^ 1, ks + 1);
        SWALL();
        bf16x8 fh0, fl0, fh1, fl1;
        split8(fx0[fc], fy0[fc], fh0, fl0);
        split8(fx1[fc], fy1[fc], fh1, fl1);
        #pragma unroll
        for (int m = 0; m < 5; ++m) {
            acc[0][m] = MFMA(wph[wc][m], fh0, acc[0][m]);
            acc[0][m] = MFMA(wph[wc][m], fl0, acc[0][m]);
            acc[0][m] = MFMA(wpl[wc][m], fh0, acc[0][m]);
            acc[1][m] = MFMA(wph[wc][m], fh1, acc[1][m]);
            acc[1][m] = MFMA(wph[wc][m], fl1, acc[1][m]);
            acc[1][m] = MFMA(wpl[wc][m], fh1, acc[1][m]);
        }
        SWALL();
    }
#undef P1_FEAT
#undef P1_WE

    // ---- merge + softmax, one 16-row strip at a time -----------------------
    #pragma unroll
    for (int s = 0; s < 2; ++s) {
        #pragma unroll
        for (int m = 0; m < 5; ++m)
            #pragma unroll
            for (int r = 0; r < 4; ++r)
                S[h][lr][16 * m + 4 * lg + r] = acc[s][m][r];
        __syncthreads();
        {
            const int srow = 4 * h + (lane >> 4), scol = lane & 15;
            float v5[6];
            float mx = -3.0e38f;
            #pragma unroll
            for (int j = 0; j < 6; ++j) {
                const int n = scol + 16 * j;
                float sv = 0.f;
                if (j < 5) {
                    sv = S[0][srow][n] + S[1][srow][n] + S[2][srow][n] + S[3][srow][n];
                    if (n < NW) mx = fmaxf(mx, sv);
                }
                v5[j] = sv;
            }
            mx = fmaxf(mx, __shfl_xor(mx, 1));
            mx = fmaxf(mx, __shfl_xor(mx, 2));
            mx = fmaxf(mx, __shfl_xor(mx, 4));
            mx = fmaxf(mx, __shfl_xor(mx, 8));
            float sum = 0.f;
            #pragma unroll
            for (int j = 0; j < 6; ++j) {
                const int n = scol + 16 * j;
                const float e = (n < NW) ? __expf(v5[j] - mx) : 0.f;
                v5[j] = e; sum += e;
            }
            sum += __shfl_xor(sum, 1);
            sum += __shfl_xor(sum, 2);
            sum += __shfl_xor(sum, 4);
            sum += __shfl_xor(sum, 8);
            const float inv = 1.0f / sum;
            #pragma unroll
            for (int j = 0; j < 6; ++j) {
                const int n = scol + 16 * j;
                u16 ph, pl; split1(v5[j] * inv, ph, pl);
                Ph[16 * s + srow][n] = ph; Pl[16 * s + srow][n] = pl;
            }
        }
        __syncthreads();
    }

    // ---- Phase 3: out^T[kout][c] = weT . P^T; 2-deep 3-slot weT ring ------
    bf16x8 pbh[2][3], pbl[2][3];
    #pragma unroll
    for (int s = 0; s < 2; ++s)
        #pragma unroll
        for (int ksn = 0; ksn < 3; ++ksn) {
            pbh[s][ksn] = *(const bf16x8*)&Ph[16 * s + lr][32 * ksn + 8 * lg];
            pbl[s][ksn] = *(const bf16x8*)&Pl[16 * s + lr][32 * ksn + 8 * lg];
        }
    const bf16x8* th = weT_hi + (size_t)b * HW2_ * 12;
    const bf16x8* tl = weT_lo + (size_t)b * HW2_ * 12;
    float* orow0 = out + (size_t)(b * C_ + c0 + lr) * HW2_;
    float* orow1 = orow0 + 16 * HW2_;

    bf16x8 wa[3][3], wb[3][3];
#define P3_LOAD(sl, ttv) do {                                       \
        const int row_ = h * 256 + (ttv) * 16 + lr;                 \
        _Pragma("unroll")                                           \
        for (int k_ = 0; k_ < 3; ++k_) {                            \
            wa[sl][k_] = th[row_ * 12 + 4 * k_ + lg];               \
            wb[sl][k_] = tl[row_ * 12 + 4 * k_ + lg];               \
        } } while (0)

    P3_LOAD(0, 0); P3_LOAD(1, 1);
    SWALL();
    #pragma unroll
    for (int tt = 0; tt < 16; ++tt) {
        const int cur = tt % 3;
        if (tt < 14) P3_LOAD((tt + 2) % 3, tt + 2);
        SWALL();
        f32x4 o0 = (f32x4)0.0f, o1 = (f32x4)0.0f;
        #pragma unroll
        for (int ksn = 0; ksn < 3; ++ksn) {
            o0 = MFMA(wa[cur][ksn], pbh[0][ksn], o0);
            o0 = MFMA(wa[cur][ksn], pbl[0][ksn], o0);
            o0 = MFMA(wb[cur][ksn], pbh[0][ksn], o0);
            o1 = MFMA(wa[cur][ksn], pbh[1][ksn], o1);
            o1 = MFMA(wa[cur][ksn], pbl[1][ksn], o1);
            o1 = MFMA(wb[cur][ksn], pbh[1][ksn], o1);
        }
        const int col = h * 256 + tt * 16 + 4 * lg;
        *(float4*)(orow0 + col) = make_float4(o0[0], o0[1], o0[2], o0[3]);
        *(float4*)(orow1 + col) = make_float4(o1[0], o1[1], o1[2], o1[3]);
        SWALL();
    }
#undef P3_LOAD
}

// ---------------------------------------------------------------------------
extern "C" void kernel_launch(void* const* d_in, const int* in_sizes, int n_in,
                              void* d_out, int out_size, void* d_ws, size_t ws_size,
                              hipStream_t stream) {
    (void)in_sizes; (void)n_in; (void)out_size; (void)ws_size;
    const float* feat     = (const float*)d_in[0];
    const float* word_emb = (const float*)d_in[1];
    const float* W_fc     = (const float*)d_in[2];
    const float* b_fc     = (const float*)d_in[3];

    bf16x8* we_hi  = (bf16x8*)d_ws;
    bf16x8* we_lo  = we_hi  + WE_ELN;
    bf16x8* weT_hi = we_lo  + WE_ELN;
    bf16x8* weT_lo = weT_hi + WET_ELN;

    we_gemm<<<512, 256, 0, stream>>>(word_emb, W_fc, b_fc, we_hi, we_lo, weT_hi, weT_lo);
    attn_mfma<<<512, 256, 0, stream>>>(feat, we_hi, we_lo, weT_hi, weT_lo, (float*)d_out);
}

// Round 7
// 179.392 us; speedup vs baseline: 1.0275x; 1.0020x over previous
//
#include <hip/hip_runtime.h>

#define B_    32
#define C_    512
#define HW2_  1024
#define NW    77
#define NP    80     // n padded to 80 (5 x 16 MFMA rows)
#define NPT   96     // n pitch for P (3 K-steps of 32), cols >=77: P=0
#define WD    256

typedef unsigned int   uint32;
typedef unsigned short u16;
typedef __attribute__((ext_vector_type(8))) short bf16x8;  // MFMA A/B frag (4 VGPR)
typedef __attribute__((ext_vector_type(4))) float f32x4;   // MFMA C/D frag

#define MFMA(a, b, c) __builtin_amdgcn_mfma_f32_16x16x32_bf16(a, b, c, 0, 0, 0)
#define SWALL() __builtin_amdgcn_sched_barrier(0)

// workspace element counts (bf16x8 = 16 B units)
// we planes:  [b][q=16][n=80][kloc=64]  -> idx = ((b*16+q)*80+n)*8 + kloc/8
// weT planes: [b][kout=1024][n=96]      -> idx = (b*1024+kout)*12 + n/8
#define WE_ELN   ((size_t)B_ * 16 * NP * 8)     // 327680
#define WET_ELN  ((size_t)B_ * HW2_ * 12)       // 393216

// fp32 -> (hi, lo) bf16 split. hi = truncation, residual exact, lo = RNE.
__device__ __forceinline__ void split1(float x, u16 &h, u16 &l) {
    uint32 u = __float_as_uint(x);
    h = (u16)(u >> 16);
    float r = x - __uint_as_float(u & 0xffff0000u);   // exact
    uint32 v = __float_as_uint(r);
    l = (u16)((v + 0x7fffu + ((v >> 16) & 1u)) >> 16);
}

__device__ __forceinline__ void split8(float4 a, float4 b, bf16x8 &h, bf16x8 &l) {
    float v[8] = {a.x, a.y, a.z, a.w, b.x, b.y, b.z, b.w};
    #pragma unroll
    for (int i = 0; i < 8; ++i) {
        u16 hh, ll; split1(v[i], hh, ll);
        h[i] = (short)hh; l[i] = (short)ll;
    }
}

// ---------------------------------------------------------------------------
// Kernel 1: we = word_emb @ W_fc^T + b_fc via MFMA (4-term split fused).
// 512 thr = 8 waves: wave (w = h&3, nh = h>>2) owns 16 kout x (nh? 2:3)
// n-tiles. 2 blocks/CU x 8 waves = 16 waves/CU (50% occ) -- TLP hides latency.
// grid 512 = 32 b x 16 k-chunks, b -> XCD b%8 (matches attn).
// ---------------------------------------------------------------------------
__global__ __launch_bounds__(512, 4) void we_gemm(
    const float* __restrict__ word_emb, const float* __restrict__ W_fc,
    const float* __restrict__ b_fc,
    bf16x8* __restrict__ we_hi, bf16x8* __restrict__ we_lo,
    bf16x8* __restrict__ weT_hi, bf16x8* __restrict__ weT_lo)
{
    __shared__ __align__(16) uint32 HL[NP][68];   // (hi<<16)|lo, 21.8 KB

    const int id = blockIdx.x;
    const int b  = (id & 7) + 8 * (id >> 7);      // XCD = id%8 = b%8
    const int q  = (id >> 3) & 15;
    const int kb = q * 64;
    const int t  = threadIdx.x;
    const int h  = t >> 6;                        // wave 0..7
    const int w  = h & 3, nh = h >> 2;
    const int lane = t & 63, lr = lane & 15, lg = lane >> 4;
    const int kout = kb + 16 * w + lr;
    const int m0 = nh ? 3 : 0;                    // n-tile range per wave
    const int mc = nh ? 2 : 3;

    // ---- hoist the W row in two 4-ks chunks (reused across all ks) --------
    const float* wrow = W_fc + kout * WD;
    bf16x8 bh[8], bl[8];
    #pragma unroll
    for (int c = 0; c < 2; ++c) {
        float4 wx[4], wy[4];
        #pragma unroll
        for (int i = 0; i < 4; ++i) {
            const int dk = (c * 4 + i) * 32 + 8 * lg;
            wx[i] = *(const float4*)(wrow + dk);
            wy[i] = *(const float4*)(wrow + dk + 4);
        }
        SWALL();
        #pragma unroll
        for (int i = 0; i < 4; ++i) split8(wx[i], wy[i], bh[c * 4 + i], bl[c * 4 + i]);
    }

    f32x4 acc[3];
    #pragma unroll
    for (int mm = 0; mm < 3; ++mm) acc[mm] = (f32x4)0.0f;

    const float* emb = word_emb + b * NW * WD;

    #pragma unroll
    for (int ks = 0; ks < 8; ++ks) {
        const int dk = ks * 32 + 8 * lg;
        bf16x8 ah[3], al[3];
        #pragma unroll
        for (int mm = 0; mm < 3; ++mm) {
            if (mm < mc) {
                const int n = 16 * (m0 + mm) + lr;
                float4 x = make_float4(0.f, 0.f, 0.f, 0.f), y = x;
                if (n < NW) {
                    const float* p = emb + n * WD + dk;
                    x = *(const float4*)p; y = *(const float4*)(p + 4);
                }
                split8(x, y, ah[mm], al[mm]);
            }
        }
        #pragma unroll
        for (int mm = 0; mm < 3; ++mm) {
            if (mm < mc) {
                acc[mm] = MFMA(ah[mm], bh[ks], acc[mm]);
                acc[mm] = MFMA(ah[mm], bl[ks], acc[mm]);
                acc[mm] = MFMA(al[mm], bh[ks], acc[mm]);
                acc[mm] = MFMA(al[mm], bl[ks], acc[mm]);
            }
        }
    }

    const float bias = b_fc[kout];
    #pragma unroll
    for (int mm = 0; mm < 3; ++mm) {
        if (mm < mc) {
            #pragma unroll
            for (int r = 0; r < 4; ++r) {
                u16 hh, ll; split1(acc[mm][r] + bias, hh, ll);
                HL[16 * (m0 + mm) + 4 * lg + r][16 * w + lr] = ((uint32)hh << 16) | ll;
            }
        }
    }
    __syncthreads();

    // we planes: [b][q][n][64k] -> contiguous runs
    for (int u = t; u < 640; u += 512) {
        const int n = u >> 3, c8 = (u & 7) * 8;
        uint4 p0 = *(const uint4*)&HL[n][c8];
        uint4 p1 = *(const uint4*)&HL[n][c8 + 4];
        const uint32 pw[8] = {p0.x, p0.y, p0.z, p0.w, p1.x, p1.y, p1.z, p1.w};
        bf16x8 hv, lv;
        #pragma unroll
        for (int i = 0; i < 8; ++i) {
            hv[i] = (short)(pw[i] >> 16);
            lv[i] = (short)(pw[i] & 0xffffu);
        }
        const int o = ((b * 16 + q) * NP + n) * 8 + (u & 7);
        we_hi[o] = hv; we_lo[o] = lv;
    }
    // weT planes: [b][kout][96] -> consecutive threads write consecutive 16 B
    #pragma unroll
    for (int v0 = 0; v0 < 1536; v0 += 512) {
        const int v = v0 + t;
        const int sel = v >= 768;
        const int r2  = sel ? v - 768 : v;
        const int row = r2 / 12, g = r2 % 12;
        bf16x8 val;
        #pragma unroll
        for (int i = 0; i < 8; ++i) {
            const int n = g * 8 + i;
            const uint32 p = (n < NP) ? HL[n][row] : 0u;
            val[i] = (short)(sel ? (p & 0xffffu) : (p >> 16));
        }
        (sel ? weT_lo : weT_hi)[(b * HW2_ + kb + row) * 12 + g] = val;
    }
}

// ---------------------------------------------------------------------------
// Kernel 2: fused scores^T -> softmax -> out via MFMA (3-term split).
// 512 thr = 8 waves; block = 32 c-rows. Phase 1: wave h = K-eighth (128).
// Phase 3: wave h = kout-eighth (128 rows). 2 blocks/CU x 8 waves = 16
// waves/CU (50% occ). Plain loads -- TLP hides latency (ILP attempts were
// neutral in r4-r6). grid 512 = 32 b x 16 c-blocks, XCD-swizzled per batch.
// ---------------------------------------------------------------------------
__global__ __launch_bounds__(512, 4) void attn_mfma(
    const float* __restrict__ feat,
    const bf16x8* __restrict__ we_hi, const bf16x8* __restrict__ we_lo,
    const bf16x8* __restrict__ weT_hi, const bf16x8* __restrict__ weT_lo,
    float* __restrict__ out)
{
    __shared__ __align__(16) float S[8][16][84];  // partial scores (43 KB)
    __shared__ __align__(16) u16   Ph[32][NPT];   // P hi (6 KB)
    __shared__ __align__(16) u16   Pl[32][NPT];   // P lo (6 KB)

    const int id  = blockIdx.x;
    const int b   = (id & 7) + 8 * (id >> 7);     // batch -> XCD id&7 (=b%8)
    const int c0  = ((id >> 3) & 15) * 32;        // block's 32 c rows

    const int t    = threadIdx.x;
    const int h    = t >> 6;                      // wave = K-eighth, 0..7
    const int lane = t & 63, lr = lane & 15, lg = lane >> 4;

    const float* frow0 = feat + (size_t)(b * C_ + c0 + lr) * HW2_;
    const float* frow1 = frow0 + 16 * HW2_;

    // ---- Phase 1: scores^T[n][c], 2 strips, K-eighth per wave -------------
    f32x4 acc[2][5];
    #pragma unroll
    for (int s = 0; s < 2; ++s)
        #pragma unroll
        for (int m = 0; m < 5; ++m) acc[s][m] = (f32x4)0.0f;

    #pragma unroll
    for (int ks = 0; ks < 4; ++ks) {
        const int kk = h * 128 + ks * 32 + 8 * lg;
        bf16x8 fh0, fl0, fh1, fl1;
        {   float4 x = *(const float4*)(frow0 + kk);
            float4 y = *(const float4*)(frow0 + kk + 4);
            split8(x, y, fh0, fl0); }
        {   float4 x = *(const float4*)(frow1 + kk);
            float4 y = *(const float4*)(frow1 + kk + 4);
            split8(x, y, fh1, fl1); }
        const int qb  = (b * 16 + 2 * h + (ks >> 1)) * NP;
        const int sub = (ks & 1) * 4 + lg;
        #pragma unroll
        for (int m = 0; m < 5; ++m) {
            const int o = (qb + 16 * m + lr) * 8 + sub;
            const bf16x8 ah = we_hi[o];
            const bf16x8 al = we_lo[o];
            acc[0][m] = MFMA(ah, fh0, acc[0][m]);
            acc[0][m] = MFMA(ah, fl0, acc[0][m]);
            acc[0][m] = MFMA(al, fh0, acc[0][m]);
            acc[1][m] = MFMA(ah, fh1, acc[1][m]);
            acc[1][m] = MFMA(ah, fl1, acc[1][m]);
            acc[1][m] = MFMA(al, fh1, acc[1][m]);
        }
    }

    // ---- merge (8 partials) + softmax, one 16-row strip at a time ---------
    #pragma unroll
    for (int s = 0; s < 2; ++s) {
        #pragma unroll
        for (int m = 0; m < 5; ++m)
            #pragma unroll
            for (int r = 0; r < 4; ++r)
                S[h][lr][16 * m + 4 * lg + r] = acc[s][m][r];
        __syncthreads();
        {
            // wave h owns 2 rows: srow = 2h + (lane>>5); 32 lanes per row
            const int srow = 2 * h + (lane >> 5), col0 = lane & 31;
            float v3[3];
            float mx = -3.0e38f;
            #pragma unroll
            for (int j = 0; j < 3; ++j) {
                const int n = col0 + 32 * j;
                float sv = S[0][srow][n] + S[1][srow][n] + S[2][srow][n] + S[3][srow][n]
                         + S[4][srow][n] + S[5][srow][n] + S[6][srow][n] + S[7][srow][n];
                if (n < NW) mx = fmaxf(mx, sv);
                v3[j] = sv;
            }
            mx = fmaxf(mx, __shfl_xor(mx, 1));
            mx = fmaxf(mx, __shfl_xor(mx, 2));
            mx = fmaxf(mx, __shfl_xor(mx, 4));
            mx = fmaxf(mx, __shfl_xor(mx, 8));
            mx = fmaxf(mx, __shfl_xor(mx, 16));
            float sum = 0.f;
            #pragma unroll
            for (int j = 0; j < 3; ++j) {
                const int n = col0 + 32 * j;
                const float e = (n < NW) ? __expf(v3[j] - mx) : 0.f;
                v3[j] = e; sum += e;
            }
            sum += __shfl_xor(sum, 1);
            sum += __shfl_xor(sum, 2);
            sum += __shfl_xor(sum, 4);
            sum += __shfl_xor(sum, 8);
            sum += __shfl_xor(sum, 16);
            const float inv = 1.0f / sum;
            #pragma unroll
            for (int j = 0; j < 3; ++j) {
                const int n = col0 + 32 * j;
                u16 ph, pl; split1(v3[j] * inv, ph, pl);
                Ph[16 * s + srow][n] = ph; Pl[16 * s + srow][n] = pl;
            }
        }
        __syncthreads();
    }

    // ---- Phase 3: out^T[kout][c] = weT . P^T; wave h owns kout-eighth -----
    bf16x8 pbh[2][3], pbl[2][3];
    #pragma unroll
    for (int s = 0; s < 2; ++s)
        #pragma unroll
        for (int ksn = 0; ksn < 3; ++ksn) {
            pbh[s][ksn] = *(const bf16x8*)&Ph[16 * s + lr][32 * ksn + 8 * lg];
            pbl[s][ksn] = *(const bf16x8*)&Pl[16 * s + lr][32 * ksn + 8 * lg];
        }
    const bf16x8* th = weT_hi + (size_t)b * HW2_ * 12;
    const bf16x8* tl = weT_lo + (size_t)b * HW2_ * 12;
    float* orow0 = out + (size_t)(b * C_ + c0 + lr) * HW2_;
    float* orow1 = orow0 + 16 * HW2_;

    #pragma unroll
    for (int tt = 0; tt < 8; ++tt) {
        const int row = h * 128 + tt * 16 + lr;
        bf16x8 wa[3], wb[3];
        #pragma unroll
        for (int ksn = 0; ksn < 3; ++ksn) {
            wa[ksn] = th[row * 12 + 4 * ksn + lg];
            wb[ksn] = tl[row * 12 + 4 * ksn + lg];
        }
        f32x4 o0 = (f32x4)0.0f, o1 = (f32x4)0.0f;
        #pragma unroll
        for (int ksn = 0; ksn < 3; ++ksn) {
            o0 = MFMA(wa[ksn], pbh[0][ksn], o0);
            o0 = MFMA(wa[ksn], pbl[0][ksn], o0);
            o0 = MFMA(wb[ksn], pbh[0][ksn], o0);
            o1 = MFMA(wa[ksn], pbh[1][ksn], o1);
            o1 = MFMA(wa[ksn], pbl[1][ksn], o1);
            o1 = MFMA(wb[ksn], pbh[1][ksn], o1);
        }
        const int col = h * 128 + tt * 16 + 4 * lg;
        *(float4*)(orow0 + col) = make_float4(o0[0], o0[1], o0[2], o0[3]);
        *(float4*)(orow1 + col) = make_float4(o1[0], o1[1], o1[2], o1[3]);
    }
}

// ---------------------------------------------------------------------------
extern "C" void kernel_launch(void* const* d_in, const int* in_sizes, int n_in,
                              void* d_out, int out_size, void* d_ws, size_t ws_size,
                              hipStream_t stream) {
    (void)in_sizes; (void)n_in; (void)out_size; (void)ws_size;
    const float* feat     = (const float*)d_in[0];
    const float* word_emb = (const float*)d_in[1];
    const float* W_fc     = (const float*)d_in[2];
    const float* b_fc     = (const float*)d_in[3];

    bf16x8* we_hi  = (bf16x8*)d_ws;
    bf16x8* we_lo  = we_hi  + WE_ELN;
    bf16x8* weT_hi = we_lo  + WE_ELN;
    bf16x8* weT_lo = weT_hi + WET_ELN;

    we_gemm<<<512, 512, 0, stream>>>(word_emb, W_fc, b_fc, we_hi, we_lo, weT_hi, weT_lo);
    attn_mfma<<<512, 512, 0, stream>>>(feat, we_hi, we_lo, weT_hi, weT_lo, (float*)d_out);
}